// Round 12
// baseline (159.468 us; speedup 1.0000x reference)
//
#include <hip/hip_runtime.h>
#include <hip/hip_bf16.h>

typedef __bf16 bf16;
typedef __attribute__((ext_vector_type(4)))  __bf16 bf16x4;
typedef __attribute__((ext_vector_type(8)))  __bf16 bf16x8;
typedef __attribute__((ext_vector_type(16))) float  f32x16;

#define B_   512
#define NC_  512
#define K_   4
#define S_   8
#define H_   128
#define D_   64
#define XROW (NC_ * K_)
#define NITER 32        // 512 items / (2 groups * 8 items/iter)

// pi: swap bits 2,3 of within-32 index (involution). Hidden dims stored
// physically permuted so the 32x32 MFMA C/D register layout of layer k IS
// the B-fragment layout of layer k+1 (r3/r5/r8-verified algebra).
static __device__ __forceinline__ int swap23(int v) {
    return (v & ~12) | ((v & 4) << 1) | ((v & 8) >> 1);
}

// Round-12: FORCED LDS diet on the round-11 pipeline. Round-8's "null" was
// a failed implementation: VGPR stayed 60 (predicted 76-80) -> the
// allocator rematerialized the hoisted ds_reads inside the loop; the diet
// never physically happened, so "LDS doesn't matter" was never tested.
// Redo with coercion: (1) hkeep[2] holds own h1 frags across the barrier
// (+8 regs, -2 HX reads/iter); (2) w2h0/w2h1 hoisted W2 frags pinned with
// opaque asm so the ds_read cannot be remat'd (+8 regs, -2 SW2 reads/iter).
// CU LDS traffic -20%. Tells: VGPR ~76-80 AND WRITE_SIZE still 8 MB.
#define BARSYNC()                                            \
    do {                                                     \
        asm volatile("s_waitcnt lgkmcnt(0)" ::: "memory");   \
        __builtin_amdgcn_s_barrier();                        \
    } while (0)

__global__ __launch_bounds__(512, 4)
void jt_mlp_kernel(const int*   __restrict__ x,
                   const float* __restrict__ W1g, const float* __restrict__ b1g,
                   const float* __restrict__ W2g, const float* __restrict__ b2g,
                   const float* __restrict__ W3g, const float* __restrict__ b3g,
                   float* __restrict__ out)
{
    // Swizzled weights: element (row p, k) at p*rowlen + ch*8 + (k&7),
    //   W1: ch = (k>>3) ^ (p&7)
    //   W2: ch = (k>>3) ^ (p&15) ^ ((p&16)>>2)
    __shared__ __align__(16) bf16 SW2[128 * 128];       // 32 KB
    __shared__ __align__(16) bf16 HX0[128 * 64];        // 16 KB (also W1 staging)
    __shared__ __align__(16) bf16 HX1[128 * 64];        // 16 KB
    __shared__ __align__(16) bf16 SW3[8 * 128];         // 2 KB
    __shared__ __align__(16) float LX[2][2][3][64][4];  // 12 KB [buf][g][qs-1]
    __shared__ __align__(16) bf16 OHLUT[16 * 8];        // 256 B

    const int tid  = threadIdx.x;
    const int lane = tid & 63;
    const int ws   = __builtin_amdgcn_readfirstlane(tid >> 6);  // 0..7 scalar
    const int g    = ws >> 2;       // item group 0,1
    const int qs   = ws & 3;        // H quarter 0..3 (rows 32qs..32qs+31)
    const int l31  = lane & 31;
    const int lhi  = lane >> 5;
    const int kk   = l31 & 3;
    const int n    = blockIdx.x;    // clique (512 blocks, 2 resident/CU)

    const float* W1p = W1g + (size_t)n * (D_ * H_);
    const float* W2p = W2g + (size_t)n * (H_ * H_);
    const float* W3p = W3g + (size_t)n * (H_ * S_);
    const float* b1p = b1g + n * H_;
    const float* b2p = b2g + n * H_;
    const float* b3p = b3g + n * S_;

    const int p31 = swap23(l31);
    const bf16 one = (bf16)1.0f, zero = (bf16)0.0f;

    // ============ stage weights into LDS (coalesced float4; r8-proven) ============
    // One-hot LUT: entry 0 = zeros (sel=-1); entry j+1 = one-hot(j).
    if (tid < 16) {
        bf16x8 v;
#pragma unroll
        for (int j = 0; j < 8; ++j) v[j] = (tid == j + 1) ? one : zero;
        *(bf16x8*)&OHLUT[tid * 8] = v;
    }
    // W1 -> HX0 (temporarily), staged by tid<256. k<8 rows carry +b1;
    // root n==0 zeroes k<32 first.
    if (tid < 256) {
        const int c0 = (tid & 31) * 4;
        const int k0 = (tid >> 5) * 8;          // 0..56
        float rows[8][4];
#pragma unroll
        for (int i = 0; i < 8; ++i) {
            float4 t4 = *(const float4*)(W1p + (k0 + i) * H_ + c0);
            if (n == 0 && k0 < 32) t4 = make_float4(0.f, 0.f, 0.f, 0.f);
            rows[i][0] = t4.x; rows[i][1] = t4.y; rows[i][2] = t4.z; rows[i][3] = t4.w;
        }
        if (k0 == 0) {
            const float4 bb = *(const float4*)(b1p + c0);
#pragma unroll
            for (int i = 0; i < 8; ++i) {
                rows[i][0] += bb.x; rows[i][1] += bb.y;
                rows[i][2] += bb.z; rows[i][3] += bb.w;
            }
        }
#pragma unroll
        for (int j2 = 0; j2 < 4; ++j2) {
            const int c = c0 + j2;
            const int p = (c & ~31) | swap23(c & 31);
            const int ch = (k0 >> 3) ^ (p & 7);
            bf16x4 lo, hi;
#pragma unroll
            for (int i = 0; i < 4; ++i) {
                lo[i] = (bf16)rows[i][j2];
                hi[i] = (bf16)rows[4 + i][j2];
            }
            *(bf16x4*)&HX0[p * 64 + ch * 8 + 0] = lo;
            *(bf16x4*)&HX0[p * 64 + ch * 8 + 4] = hi;
        }
    }
    // W2 -> SW2 (5-bit swizzle): all 512 threads, one 8-row block each
    {
        const int c0 = (tid & 31) * 4;
        const int k0 = (tid >> 5) * 8;          // 0..120
        float rows[8][4];
#pragma unroll
        for (int i = 0; i < 8; ++i) {
            const float4 t4 = *(const float4*)(W2p + (k0 + i) * H_ + c0);
            rows[i][0] = t4.x; rows[i][1] = t4.y; rows[i][2] = t4.z; rows[i][3] = t4.w;
        }
#pragma unroll
        for (int j2 = 0; j2 < 4; ++j2) {
            const int c = c0 + j2;
            const int p = (c & ~31) | swap23(c & 31);
            const int ch = (k0 >> 3) ^ (p & 15) ^ ((p & 16) >> 2);
            bf16x4 lo, hi;
#pragma unroll
            for (int i = 0; i < 4; ++i) {
                lo[i] = (bf16)rows[i][j2];
                hi[i] = (bf16)rows[4 + i][j2];
            }
            *(bf16x4*)&SW2[p * 128 + ch * 8 + 0] = lo;
            *(bf16x4*)&SW2[p * 128 + ch * 8 + 4] = hi;
        }
    }
    // W3^T[s][k] -> SW3
    if (tid < 128) {
        const int s = tid >> 4, kc = tid & 15, k0 = kc * 8;
        float vv[8];
#pragma unroll
        for (int i = 0; i < 8; ++i) vv[i] = W3p[(k0 + i) * S_ + s];
        const int ch = kc ^ s;
        bf16x4 lo, hi;
#pragma unroll
        for (int i = 0; i < 4; ++i) { lo[i] = (bf16)vv[i]; hi[i] = (bf16)vv[4 + i]; }
        *(bf16x4*)&SW3[s * 128 + ch * 8 + 0] = lo;
        *(bf16x4*)&SW3[s * 128 + ch * 8 + 4] = hi;
    }
    __syncthreads();

    const int swz = (l31 & 15) ^ ((l31 & 16) >> 2);
    const int pq  = (32 * qs + l31) * 128;    // W2 row base (C rows 32qs..+31)
    const int g8  = g * 8;

    // ---- W1 fragments for this wave's H-quarter (rows 32qs..32qs+31) ----
    bf16x8 w1f[4];
#pragma unroll
    for (int kt = 0; kt < 4; ++kt)
        w1f[kt] = *(const bf16x8*)
            &HX0[(32 * qs + l31) * 64 + (((kt << 1) + lhi) ^ (l31 & 7)) * 8];
    // ---- W3 fragments (this wave's chunks 2qs, 2qs+1) ----
    const int s2 = l31 & 7;   // lanes 8..31 duplicate state rows (outputs unused)
    bf16x8 w3f[2];
#pragma unroll
    for (int e = 0; e < 2; ++e)
        w3f[e] = *(const bf16x8*)
            &SW3[s2 * 128 + ((((2 * qs + e) << 1) + lhi) ^ s2) * 8];
    // ---- hoisted W2 fragments for gc=0,1 -- asm-pinned against remat ----
    bf16x8 w2h0 = *(const bf16x8*)&SW2[pq + (((0 << 1) + lhi) ^ swz) * 8];
    bf16x8 w2h1 = *(const bf16x8*)&SW2[pq + (((1 << 1) + lhi) ^ swz) * 8];
    asm volatile("" : "+v"(w2h0));
    asm volatile("" : "+v"(w2h1));
    // ---- bias frags ----
    bf16x8 w2b, onef;
#pragma unroll
    for (int j = 0; j < 8; ++j) { w2b[j] = zero; onef[j] = zero; }
    w2b[0] = lhi ? zero : (bf16)b2p[32 * qs + p31];
    onef[0] = lhi ? zero : one;
    const float4 b3q = *(const float4*)(b3p + 4 * lhi);

    f32x16 zf;
#pragma unroll
    for (int i = 0; i < 16; ++i) zf[i] = 0.f;

    // -------- x for item 0 --------
    const int itbase = g * 8 + (l31 >> 2);
    int4 xo_c, xp_c, xo_e;
    {
        const int* xb = x + (size_t)itbase * XROW + n * K_;
        xo_c = *(const int4*)xb;
        xp_c = (n > 0) ? *(const int4*)(xb - K_) : make_int4(0, 0, 0, 0);
    }

    __syncthreads();   // all w1f reads from HX0 done -> HX0 becomes h1 buffer

    bf16x8 hkeep[2];   // own 2 h1 chunks, kept across the barrier

    // ======== pipeline prologue: L1(0) -> HX0 ========
    {
        const int4 xo = xo_c, xp = xp_c;
        {   // prefetch item 1
            const int* xb = x + (size_t)(itbase + 16) * XROW + n * K_;
            xo_c = *(const int4*)xb;
            xp_c = (n > 0) ? *(const int4*)(xb - K_) : make_int4(0, 0, 0, 0);
        }
        int sel[4];
        sel[0] = (n > 0) ? (lhi ? xp.y : xp.x) : (lhi ? -1 : 0);
        sel[1] = (n > 0) ? (lhi ? xp.w : xp.z) : -1;
        sel[2] = (kk > (lhi ? 1 : 0)) ? (lhi ? xo.y : xo.x) : -1;
        sel[3] = (kk > (lhi ? 3 : 2)) ? (lhi ? xo.w : xo.z) : -1;
        f32x16 A = zf;
#pragma unroll
        for (int kt = 0; kt < 4; ++kt) {
            const bf16x8 bf1 = *(const bf16x8*)&OHLUT[(sel[kt] + 1) * 8];
            A = __builtin_amdgcn_mfma_f32_32x32x16_bf16(w1f[kt], bf1, A, 0, 0, 0);
        }
#pragma unroll
        for (int e = 0; e < 2; ++e) {
            bf16x8 hf;
#pragma unroll
            for (int j = 0; j < 8; ++j)
                hf[j] = (bf16)fmaxf(A[8 * e + j], 0.f);
            hkeep[e] = hf;
            *(bf16x8*)&HX0[(g8 + 2 * qs + e) * 512 + lane * 8] = hf;
        }
        xo_e = xo;
    }
    BARSYNC();

// Epilogue for item (ITEME) using partial L + LX[LXB] (post-barrier).
#define EPILOGUE(LXB, ITEME)                                                   \
    if (qs == 0) {                                                             \
        const float4 P0 = *(const float4*)&LX[LXB][g][0][lane][0];             \
        const float4 P1 = *(const float4*)&LX[LXB][g][1][lane][0];             \
        const float4 P2 = *(const float4*)&LX[LXB][g][2][lane][0];             \
        float Ls0 = L[0] + P0.x + P1.x + P2.x + b3q.x;                         \
        float Ls1 = L[1] + P0.y + P1.y + P2.y + b3q.y;                         \
        float Ls2 = L[2] + P0.z + P1.z + P2.z + b3q.z;                         \
        float Ls3 = L[3] + P0.w + P1.w + P2.w + b3q.w;                         \
        float m4 = fmaxf(fmaxf(Ls0, Ls1), fmaxf(Ls2, Ls3));                    \
        const float mm = fmaxf(m4, __shfl_xor(m4, 32));                        \
        float ee = __expf(Ls0 - mm) + __expf(Ls1 - mm) +                       \
                   __expf(Ls2 - mm) + __expf(Ls3 - mm);                        \
        const float ssum = ee + __shfl_xor(ee, 32);                            \
        const int xs = (kk & 2) ? ((kk & 1) ? xo_e.w : xo_e.z)                 \
                                : ((kk & 1) ? xo_e.y : xo_e.x);                \
        const float own = (xs & 2) ? ((xs & 1) ? Ls3 : Ls2)                    \
                                   : ((xs & 1) ? Ls1 : Ls0);                   \
        const float oth = __shfl_xor(own, 32);                                 \
        const float obs = ((xs >> 2) == lhi) ? own : oth;                      \
        float lp = obs - mm - __logf(ssum);                                    \
        lp += __shfl_xor(lp, 1);                                               \
        lp += __shfl_xor(lp, 2);                                               \
        if (lhi == 0 && kk == 0)                                               \
            out[(size_t)(ITEME) * NC_ + n] = lp;                               \
    }

// Layer 2+3 for the previous item: own chunks from hkeep (no HX read),
// gc 0,1 W2 frags from pinned regs (no SW2 read).
#define L23_BODY(HR, LXB)                                                      \
        f32x16 C =                                                             \
            __builtin_amdgcn_mfma_f32_32x32x16_bf16(w2b, onef, zf, 0, 0, 0);   \
        _Pragma("unroll")                                                      \
        for (int gc = 0; gc < 8; ++gc) {                                       \
            bf16x8 hf;                                                         \
            if ((gc >> 1) == qs) {                                             \
                hf = hkeep[gc & 1];                                            \
            } else {                                                           \
                hf = *(const bf16x8*)&HR[(g8 + gc) * 512 + lane * 8];          \
            }                                                                  \
            bf16x8 f;                                                          \
            if (gc == 0)      f = w2h0;                                        \
            else if (gc == 1) f = w2h1;                                        \
            else f = *(const bf16x8*)&SW2[pq + (((gc << 1) + lhi) ^ swz) * 8]; \
            C = __builtin_amdgcn_mfma_f32_32x32x16_bf16(f, hf, C, 0, 0, 0);    \
        }                                                                      \
        f32x16 L = zf;                                                         \
        _Pragma("unroll")                                                      \
        for (int e = 0; e < 2; ++e) {                                          \
            bf16x8 hg;                                                         \
            _Pragma("unroll")                                                  \
            for (int j = 0; j < 8; ++j)                                        \
                hg[j] = (bf16)fmaxf(C[8 * e + j], 0.f);                        \
            L = __builtin_amdgcn_mfma_f32_32x32x16_bf16(w3f[e], hg, L, 0, 0, 0);\
        }                                                                      \
        if (qs != 0)                                                           \
            *(float4*)&LX[LXB][g][qs - 1][lane][0] =                           \
                make_float4(L[0], L[1], L[2], L[3]);

// One pipeline step: phase A (prio 1) = L2/L3(item KK-1 from HR/hkeep) +
// L1(item KK -> HW + hkeep); lgkm-only barrier; phase B = epilogue(KK-1).
#define ITER_BODY(KK, HR, HW, LXB)                                             \
    do {                                                                       \
        const int4 xo = xo_c, xp = xp_c;                                       \
        if ((KK) < NITER - 1) {                                                \
            const int* xb =                                                    \
                x + (size_t)(itbase + ((KK) + 1) * 16) * XROW + n * K_;        \
            xo_c = *(const int4*)xb;                                           \
            xp_c = (n > 0) ? *(const int4*)(xb - K_) : make_int4(0, 0, 0, 0);  \
        }                                                                      \
        __builtin_amdgcn_s_setprio(1);                                         \
        L23_BODY(HR, LXB)                                                      \
        /* phase A2: layer 1 for item KK */                                    \
        int sel[4];                                                            \
        sel[0] = (n > 0) ? (lhi ? xp.y : xp.x) : (lhi ? -1 : 0);               \
        sel[1] = (n > 0) ? (lhi ? xp.w : xp.z) : -1;                           \
        sel[2] = (kk > (lhi ? 1 : 0)) ? (lhi ? xo.y : xo.x) : -1;              \
        sel[3] = (kk > (lhi ? 3 : 2)) ? (lhi ? xo.w : xo.z) : -1;              \
        f32x16 A = zf;                                                         \
        _Pragma("unroll")                                                      \
        for (int kt = 0; kt < 4; ++kt) {                                       \
            const bf16x8 bf1 = *(const bf16x8*)&OHLUT[(sel[kt] + 1) * 8];      \
            A = __builtin_amdgcn_mfma_f32_32x32x16_bf16(w1f[kt], bf1, A, 0, 0, 0);\
        }                                                                      \
        _Pragma("unroll")                                                      \
        for (int e = 0; e < 2; ++e) {                                          \
            bf16x8 hf;                                                         \
            _Pragma("unroll")                                                  \
            for (int j = 0; j < 8; ++j)                                        \
                hf[j] = (bf16)fmaxf(A[8 * e + j], 0.f);                        \
            hkeep[e] = hf;                                                     \
            *(bf16x8*)&HW[(g8 + 2 * qs + e) * 512 + lane * 8] = hf;            \
        }                                                                      \
        __builtin_amdgcn_s_setprio(0);                                         \
        BARSYNC();                                                             \
        /* phase B: epilogue item KK-1 (overlaps next phase A of qs!=0) */     \
        EPILOGUE(LXB, itbase + ((KK) - 1) * 16)                                \
        xo_e = xo;                                                             \
    } while (0)

#pragma unroll 1
    for (int k = 1; k < NITER - 1; k += 2) {
        ITER_BODY(k,     HX0, HX1, 0);
        ITER_BODY(k + 1, HX1, HX0, 1);
    }
    ITER_BODY(NITER - 1, HX0, HX1, 0);   // k=31 (odd): rd HX0, wr HX1

    // ======== pipeline tail: L2/L3 + epilogue for item NITER-1 ========
    {
        L23_BODY(HX1, 1)
        BARSYNC();
        EPILOGUE(1, itbase + (NITER - 1) * 16)
    }
}

extern "C" void kernel_launch(void* const* d_in, const int* in_sizes, int n_in,
                              void* d_out, int out_size, void* d_ws, size_t ws_size,
                              hipStream_t stream) {
    const int*   x  = (const int*)d_in[0];
    const float* W1 = (const float*)d_in[1];
    const float* b1 = (const float*)d_in[2];
    const float* W2 = (const float*)d_in[3];
    const float* b2 = (const float*)d_in[4];
    const float* W3 = (const float*)d_in[5];
    const float* b3 = (const float*)d_in[6];
    float* out = (float*)d_out;
    jt_mlp_kernel<<<dim3(NC_), 512, 0, stream>>>(x, W1, b1, W2, b2, W3, b3, out);
}

// Round 13
// 155.445 us; speedup vs baseline: 1.0259x; 1.0259x over previous
//
#include <hip/hip_runtime.h>
#include <hip/hip_bf16.h>

typedef __bf16 bf16;
typedef __attribute__((ext_vector_type(4)))  __bf16 bf16x4;
typedef __attribute__((ext_vector_type(8)))  __bf16 bf16x8;
typedef __attribute__((ext_vector_type(16))) float  f32x16;

#define B_   512
#define NC_  512
#define K_   4
#define S_   8
#define H_   128
#define D_   64
#define XROW (NC_ * K_)
#define NITER 32        // 512 items / (2 groups * 8 items/iter)

// pi: swap bits 2,3 of within-32 index (involution). Hidden dims stored
// physically permuted so the 32x32 MFMA C/D register layout of layer k IS
// the B-fragment layout of layer k+1 (r3/r5/r8-verified algebra).
static __device__ __forceinline__ int swap23(int v) {
    return (v & ~12) | ((v & 4) << 1) | ((v & 8) >> 1);
}

// Round-13: C-chain split on the round-11 base (measured best, 81 us).
// r12 post-mortem killed the LDS-throughput model (real -15% LDS ops,
// conflicts -21%, time WORSE). Remaining untested mechanism: layer-2 is a
// 9-deep dependent MFMA chain; at 4 waves/SIMD in lockstep phases the
// ~32-40cyc dependent latency is only marginally hidden (4x8cyc issue).
// Split: C0 = bias + even gc (5 deep), C1 = odd gc (4 deep), merged with
// 16 VALU adds at extraction -> 8 independent MFMA streams per SIMD.
// Acc 48->64, total 128 = exactly the proven 4-wave budget.
// Fail tells: occupancy <35% or WRITE_SIZE >8MB -> quantum broke, revert.
#define BARSYNC()                                            \
    do {                                                     \
        asm volatile("s_waitcnt lgkmcnt(0)" ::: "memory");   \
        __builtin_amdgcn_s_barrier();                        \
    } while (0)

__global__ __launch_bounds__(512, 4)
void jt_mlp_kernel(const int*   __restrict__ x,
                   const float* __restrict__ W1g, const float* __restrict__ b1g,
                   const float* __restrict__ W2g, const float* __restrict__ b2g,
                   const float* __restrict__ W3g, const float* __restrict__ b3g,
                   float* __restrict__ out)
{
    // Swizzled weights: element (row p, k) at p*rowlen + ch*8 + (k&7),
    //   W1: ch = (k>>3) ^ (p&7)
    //   W2: ch = (k>>3) ^ (p&15) ^ ((p&16)>>2)
    __shared__ __align__(16) bf16 SW2[128 * 128];       // 32 KB
    __shared__ __align__(16) bf16 HX0[128 * 64];        // 16 KB (also W1 staging)
    __shared__ __align__(16) bf16 HX1[128 * 64];        // 16 KB
    __shared__ __align__(16) bf16 SW3[8 * 128];         // 2 KB
    __shared__ __align__(16) float LX[2][2][3][64][4];  // 12 KB [buf][g][qs-1]
    __shared__ __align__(16) bf16 OHLUT[16 * 8];        // 256 B

    const int tid  = threadIdx.x;
    const int lane = tid & 63;
    const int ws   = __builtin_amdgcn_readfirstlane(tid >> 6);  // 0..7 scalar
    const int g    = ws >> 2;       // item group 0,1
    const int qs   = ws & 3;        // H quarter 0..3 (rows 32qs..32qs+31)
    const int l31  = lane & 31;
    const int lhi  = lane >> 5;
    const int kk   = l31 & 3;
    const int n    = blockIdx.x;    // clique (512 blocks, 2 resident/CU)

    const float* W1p = W1g + (size_t)n * (D_ * H_);
    const float* W2p = W2g + (size_t)n * (H_ * H_);
    const float* W3p = W3g + (size_t)n * (H_ * S_);
    const float* b1p = b1g + n * H_;
    const float* b2p = b2g + n * H_;
    const float* b3p = b3g + n * S_;

    const int p31 = swap23(l31);
    const bf16 one = (bf16)1.0f, zero = (bf16)0.0f;

    // ============ stage weights into LDS (coalesced float4; r8-proven) ============
    // One-hot LUT: entry 0 = zeros (sel=-1); entry j+1 = one-hot(j).
    if (tid < 16) {
        bf16x8 v;
#pragma unroll
        for (int j = 0; j < 8; ++j) v[j] = (tid == j + 1) ? one : zero;
        *(bf16x8*)&OHLUT[tid * 8] = v;
    }
    // W1 -> HX0 (temporarily), staged by tid<256. k<8 rows carry +b1;
    // root n==0 zeroes k<32 first.
    if (tid < 256) {
        const int c0 = (tid & 31) * 4;
        const int k0 = (tid >> 5) * 8;          // 0..56
        float rows[8][4];
#pragma unroll
        for (int i = 0; i < 8; ++i) {
            float4 t4 = *(const float4*)(W1p + (k0 + i) * H_ + c0);
            if (n == 0 && k0 < 32) t4 = make_float4(0.f, 0.f, 0.f, 0.f);
            rows[i][0] = t4.x; rows[i][1] = t4.y; rows[i][2] = t4.z; rows[i][3] = t4.w;
        }
        if (k0 == 0) {
            const float4 bb = *(const float4*)(b1p + c0);
#pragma unroll
            for (int i = 0; i < 8; ++i) {
                rows[i][0] += bb.x; rows[i][1] += bb.y;
                rows[i][2] += bb.z; rows[i][3] += bb.w;
            }
        }
#pragma unroll
        for (int j2 = 0; j2 < 4; ++j2) {
            const int c = c0 + j2;
            const int p = (c & ~31) | swap23(c & 31);
            const int ch = (k0 >> 3) ^ (p & 7);
            bf16x4 lo, hi;
#pragma unroll
            for (int i = 0; i < 4; ++i) {
                lo[i] = (bf16)rows[i][j2];
                hi[i] = (bf16)rows[4 + i][j2];
            }
            *(bf16x4*)&HX0[p * 64 + ch * 8 + 0] = lo;
            *(bf16x4*)&HX0[p * 64 + ch * 8 + 4] = hi;
        }
    }
    // W2 -> SW2 (5-bit swizzle): all 512 threads, one 8-row block each
    {
        const int c0 = (tid & 31) * 4;
        const int k0 = (tid >> 5) * 8;          // 0..120
        float rows[8][4];
#pragma unroll
        for (int i = 0; i < 8; ++i) {
            const float4 t4 = *(const float4*)(W2p + (k0 + i) * H_ + c0);
            rows[i][0] = t4.x; rows[i][1] = t4.y; rows[i][2] = t4.z; rows[i][3] = t4.w;
        }
#pragma unroll
        for (int j2 = 0; j2 < 4; ++j2) {
            const int c = c0 + j2;
            const int p = (c & ~31) | swap23(c & 31);
            const int ch = (k0 >> 3) ^ (p & 15) ^ ((p & 16) >> 2);
            bf16x4 lo, hi;
#pragma unroll
            for (int i = 0; i < 4; ++i) {
                lo[i] = (bf16)rows[i][j2];
                hi[i] = (bf16)rows[4 + i][j2];
            }
            *(bf16x4*)&SW2[p * 128 + ch * 8 + 0] = lo;
            *(bf16x4*)&SW2[p * 128 + ch * 8 + 4] = hi;
        }
    }
    // W3^T[s][k] -> SW3
    if (tid < 128) {
        const int s = tid >> 4, kc = tid & 15, k0 = kc * 8;
        float vv[8];
#pragma unroll
        for (int i = 0; i < 8; ++i) vv[i] = W3p[(k0 + i) * S_ + s];
        const int ch = kc ^ s;
        bf16x4 lo, hi;
#pragma unroll
        for (int i = 0; i < 4; ++i) { lo[i] = (bf16)vv[i]; hi[i] = (bf16)vv[4 + i]; }
        *(bf16x4*)&SW3[s * 128 + ch * 8 + 0] = lo;
        *(bf16x4*)&SW3[s * 128 + ch * 8 + 4] = hi;
    }
    __syncthreads();

    const int swz = (l31 & 15) ^ ((l31 & 16) >> 2);
    const int pq  = (32 * qs + l31) * 128;    // W2 row base (C rows 32qs..+31)
    const int g8  = g * 8;

    // ---- W1 fragments for this wave's H-quarter (rows 32qs..32qs+31) ----
    bf16x8 w1f[4];
#pragma unroll
    for (int kt = 0; kt < 4; ++kt)
        w1f[kt] = *(const bf16x8*)
            &HX0[(32 * qs + l31) * 64 + (((kt << 1) + lhi) ^ (l31 & 7)) * 8];
    // ---- W3 fragments (this wave's chunks 2qs, 2qs+1) ----
    const int s2 = l31 & 7;   // lanes 8..31 duplicate state rows (outputs unused)
    bf16x8 w3f[2];
#pragma unroll
    for (int e = 0; e < 2; ++e)
        w3f[e] = *(const bf16x8*)
            &SW3[s2 * 128 + ((((2 * qs + e) << 1) + lhi) ^ s2) * 8];
    // ---- bias frags ----
    bf16x8 w2b, onef;
#pragma unroll
    for (int j = 0; j < 8; ++j) { w2b[j] = zero; onef[j] = zero; }
    w2b[0] = lhi ? zero : (bf16)b2p[32 * qs + p31];
    onef[0] = lhi ? zero : one;
    const float4 b3q = *(const float4*)(b3p + 4 * lhi);

    f32x16 zf;
#pragma unroll
    for (int i = 0; i < 16; ++i) zf[i] = 0.f;

    // -------- x for item 0 --------
    const int itbase = g * 8 + (l31 >> 2);
    int4 xo_c, xp_c, xo_e;
    {
        const int* xb = x + (size_t)itbase * XROW + n * K_;
        xo_c = *(const int4*)xb;
        xp_c = (n > 0) ? *(const int4*)(xb - K_) : make_int4(0, 0, 0, 0);
    }

    __syncthreads();   // all w1f reads from HX0 done -> HX0 becomes h1 buffer

    // ======== pipeline prologue: L1(0) -> HX0 ========
    {
        const int4 xo = xo_c, xp = xp_c;
        {   // prefetch item 1
            const int* xb = x + (size_t)(itbase + 16) * XROW + n * K_;
            xo_c = *(const int4*)xb;
            xp_c = (n > 0) ? *(const int4*)(xb - K_) : make_int4(0, 0, 0, 0);
        }
        int sel[4];
        sel[0] = (n > 0) ? (lhi ? xp.y : xp.x) : (lhi ? -1 : 0);
        sel[1] = (n > 0) ? (lhi ? xp.w : xp.z) : -1;
        sel[2] = (kk > (lhi ? 1 : 0)) ? (lhi ? xo.y : xo.x) : -1;
        sel[3] = (kk > (lhi ? 3 : 2)) ? (lhi ? xo.w : xo.z) : -1;
        f32x16 A = zf;
#pragma unroll
        for (int kt = 0; kt < 4; ++kt) {
            const bf16x8 bf1 = *(const bf16x8*)&OHLUT[(sel[kt] + 1) * 8];
            A = __builtin_amdgcn_mfma_f32_32x32x16_bf16(w1f[kt], bf1, A, 0, 0, 0);
        }
#pragma unroll
        for (int e = 0; e < 2; ++e) {
            bf16x8 hf;
#pragma unroll
            for (int j = 0; j < 8; ++j)
                hf[j] = (bf16)fmaxf(A[8 * e + j], 0.f);
            *(bf16x8*)&HX0[(g8 + 2 * qs + e) * 512 + lane * 8] = hf;
        }
        xo_e = xo;
    }
    BARSYNC();

// Epilogue for item (ITEME) using partial L + LX[LXB] (post-barrier).
#define EPILOGUE(LXB, ITEME)                                                   \
    if (qs == 0) {                                                             \
        const float4 P0 = *(const float4*)&LX[LXB][g][0][lane][0];             \
        const float4 P1 = *(const float4*)&LX[LXB][g][1][lane][0];             \
        const float4 P2 = *(const float4*)&LX[LXB][g][2][lane][0];             \
        float Ls0 = L[0] + P0.x + P1.x + P2.x + b3q.x;                         \
        float Ls1 = L[1] + P0.y + P1.y + P2.y + b3q.y;                         \
        float Ls2 = L[2] + P0.z + P1.z + P2.z + b3q.z;                         \
        float Ls3 = L[3] + P0.w + P1.w + P2.w + b3q.w;                         \
        float m4 = fmaxf(fmaxf(Ls0, Ls1), fmaxf(Ls2, Ls3));                    \
        const float mm = fmaxf(m4, __shfl_xor(m4, 32));                        \
        float ee = __expf(Ls0 - mm) + __expf(Ls1 - mm) +                       \
                   __expf(Ls2 - mm) + __expf(Ls3 - mm);                        \
        const float ssum = ee + __shfl_xor(ee, 32);                            \
        const int xs = (kk & 2) ? ((kk & 1) ? xo_e.w : xo_e.z)                 \
                                : ((kk & 1) ? xo_e.y : xo_e.x);                \
        const float own = (xs & 2) ? ((xs & 1) ? Ls3 : Ls2)                    \
                                   : ((xs & 1) ? Ls1 : Ls0);                   \
        const float oth = __shfl_xor(own, 32);                                 \
        const float obs = ((xs >> 2) == lhi) ? own : oth;                      \
        float lp = obs - mm - __logf(ssum);                                    \
        lp += __shfl_xor(lp, 1);                                               \
        lp += __shfl_xor(lp, 2);                                               \
        if (lhi == 0 && kk == 0)                                               \
            out[(size_t)(ITEME) * NC_ + n] = lp;                               \
    }

// Layer 2+3 for the previous item, SPLIT-CHAIN: C0 = bias + even gc (5
// deep), C1 = odd gc (4 deep); merged elementwise at the relu extraction.
#define L23_BODY(HR, LXB)                                                      \
        f32x16 C0 =                                                            \
            __builtin_amdgcn_mfma_f32_32x32x16_bf16(w2b, onef, zf, 0, 0, 0);   \
        f32x16 C1 = zf;                                                        \
        _Pragma("unroll")                                                      \
        for (int gc = 0; gc < 8; gc += 2) {                                    \
            const bf16x8 hf0 =                                                 \
                *(const bf16x8*)&HR[(g8 + gc) * 512 + lane * 8];               \
            const bf16x8 f0 =                                                  \
                *(const bf16x8*)&SW2[pq + (((gc << 1) + lhi) ^ swz) * 8];      \
            C0 = __builtin_amdgcn_mfma_f32_32x32x16_bf16(f0, hf0, C0, 0, 0, 0);\
            const bf16x8 hf1 =                                                 \
                *(const bf16x8*)&HR[(g8 + gc + 1) * 512 + lane * 8];           \
            const bf16x8 f1 =                                                  \
                *(const bf16x8*)&SW2[pq + ((((gc + 1) << 1) + lhi) ^ swz) * 8];\
            C1 = __builtin_amdgcn_mfma_f32_32x32x16_bf16(f1, hf1, C1, 0, 0, 0);\
        }                                                                      \
        f32x16 L = zf;                                                         \
        _Pragma("unroll")                                                      \
        for (int e = 0; e < 2; ++e) {                                          \
            bf16x8 hg;                                                         \
            _Pragma("unroll")                                                  \
            for (int j = 0; j < 8; ++j)                                        \
                hg[j] = (bf16)fmaxf(C0[8 * e + j] + C1[8 * e + j], 0.f);       \
            L = __builtin_amdgcn_mfma_f32_32x32x16_bf16(w3f[e], hg, L, 0, 0, 0);\
        }                                                                      \
        if (qs != 0)                                                           \
            *(float4*)&LX[LXB][g][qs - 1][lane][0] =                           \
                make_float4(L[0], L[1], L[2], L[3]);

// One pipeline step: phase A (prio 1) = L2/L3(item KK-1 from HR) + L1(item
// KK -> HW); lgkm-only barrier; phase B (prio 0) = epilogue(KK-1).
#define ITER_BODY(KK, HR, HW, LXB)                                             \
    do {                                                                       \
        const int4 xo = xo_c, xp = xp_c;                                       \
        if ((KK) < NITER - 1) {                                                \
            const int* xb =                                                    \
                x + (size_t)(itbase + ((KK) + 1) * 16) * XROW + n * K_;        \
            xo_c = *(const int4*)xb;                                           \
            xp_c = (n > 0) ? *(const int4*)(xb - K_) : make_int4(0, 0, 0, 0);  \
        }                                                                      \
        __builtin_amdgcn_s_setprio(1);                                         \
        L23_BODY(HR, LXB)                                                      \
        /* phase A2: layer 1 for item KK */                                    \
        int sel[4];                                                            \
        sel[0] = (n > 0) ? (lhi ? xp.y : xp.x) : (lhi ? -1 : 0);               \
        sel[1] = (n > 0) ? (lhi ? xp.w : xp.z) : -1;                           \
        sel[2] = (kk > (lhi ? 1 : 0)) ? (lhi ? xo.y : xo.x) : -1;              \
        sel[3] = (kk > (lhi ? 3 : 2)) ? (lhi ? xo.w : xo.z) : -1;              \
        f32x16 A = zf;                                                         \
        _Pragma("unroll")                                                      \
        for (int kt = 0; kt < 4; ++kt) {                                       \
            const bf16x8 bf1 = *(const bf16x8*)&OHLUT[(sel[kt] + 1) * 8];      \
            A = __builtin_amdgcn_mfma_f32_32x32x16_bf16(w1f[kt], bf1, A, 0, 0, 0);\
        }                                                                      \
        _Pragma("unroll")                                                      \
        for (int e = 0; e < 2; ++e) {                                          \
            bf16x8 hf;                                                         \
            _Pragma("unroll")                                                  \
            for (int j = 0; j < 8; ++j)                                        \
                hf[j] = (bf16)fmaxf(A[8 * e + j], 0.f);                        \
            *(bf16x8*)&HW[(g8 + 2 * qs + e) * 512 + lane * 8] = hf;            \
        }                                                                      \
        __builtin_amdgcn_s_setprio(0);                                         \
        BARSYNC();                                                             \
        /* phase B: epilogue item KK-1 (overlaps next phase A of qs!=0) */     \
        EPILOGUE(LXB, itbase + ((KK) - 1) * 16)                                \
        xo_e = xo;                                                             \
    } while (0)

#pragma unroll 1
    for (int k = 1; k < NITER - 1; k += 2) {
        ITER_BODY(k,     HX0, HX1, 0);
        ITER_BODY(k + 1, HX1, HX0, 1);
    }
    ITER_BODY(NITER - 1, HX0, HX1, 0);   // k=31 (odd): rd HX0, wr HX1

    // ======== pipeline tail: L2/L3 + epilogue for item NITER-1 ========
    {
        L23_BODY(HX1, 1)
        BARSYNC();
        EPILOGUE(1, itbase + (NITER - 1) * 16)
    }
}

extern "C" void kernel_launch(void* const* d_in, const int* in_sizes, int n_in,
                              void* d_out, int out_size, void* d_ws, size_t ws_size,
                              hipStream_t stream) {
    const int*   x  = (const int*)d_in[0];
    const float* W1 = (const float*)d_in[1];
    const float* b1 = (const float*)d_in[2];
    const float* W2 = (const float*)d_in[3];
    const float* b2 = (const float*)d_in[4];
    const float* W3 = (const float*)d_in[5];
    const float* b3 = (const float*)d_in[6];
    float* out = (float*)d_out;
    jt_mlp_kernel<<<dim3(NC_), 512, 0, stream>>>(x, W1, b1, W2, b2, W3, b3, out);
}